// Round 13
// baseline (125.682 us; speedup 1.0000x reference)
//
#include <hip/hip_runtime.h>

// spec (32, 4000, 161, 2) f32.
//   pow[b,t,k]  = re^2 + im^2
//   g0[b,t]     = sqrt((2*sum(pow[1..159]) + pow[0] + pow[160]) / 320)
//   gain[b,t]   = EMA over t: c = 0.9c + 0.1*g0  (gain[b,0]=g0[b,0])
//   new_spec    = spec / (gain + 0.001)
// Outputs flat-concat: new_spec (41,216,000 f32) then gain (128,000 f32).
//
// One dispatch (R8 flow structure + R11 line-exact phase A):
//  Block (b,c) owns 200 frames. Phase A: g0 via 2-frames-per-8-lane-group
//  (whole 64B lines consumed exactly once, 21 indep loads/lane, 3-shfl
//  reduce). Publish g0 (threadfence+flag), spin on 2 predecessors (g0 halo
//  = 383 floats), truncated-window EMA (0.9^384 < f32 eps -> exact), then
//  stream the chunk while spec is cache-hot: out = spec * inv, nt stores.
//  640 blocks x 512 thr <= 1024 co-residency slots; flag depends only on
//  own work -> deadlock-free. Flags zeroed per launch via hipMemsetAsync.

typedef float f32x4 __attribute__((ext_vector_type(4)));
typedef float f32x2 __attribute__((ext_vector_type(2)));

#define B_SZ 32
#define T_SZ 4000
#define FRAME_F 322              // floats per frame (161 bins * 2)
#define FRAMES (B_SZ * T_SZ)     // 128000
#define N_SPEC ((size_t)FRAMES * FRAME_F)  // 41,216,000
#define EMA_W 384                // 0.9^384 ~ 4e-18: below f32 resolution
#define HALO (EMA_W - 1)         // 383
#define BLOCK 512                // 8 waves
#define CHUNK 200                // frames per block
#define NCHUNK (T_SZ / CHUNK)    // 20 -> grid (20, 32) = 640 blocks
#define GRPS (CHUNK / 2)         // 100 two-frame groups per block
#define C4 (CHUNK * FRAME_F / 4) // 16100 f32x4 per chunk (exact)
#define XS_N (HALO + CHUNK)      // 583

__global__ __launch_bounds__(BLOCK) void k_flow(
    const float* __restrict__ spec, float* __restrict__ out,
    float* __restrict__ gain_out, float* __restrict__ g0,
    int* __restrict__ flags) {
  __shared__ float xs[XS_N];       // g0 window [lo, t0+CHUNK)
  __shared__ float inv_s[CHUNK];   // 1/(gain+1e-3) for owned frames

  int c  = blockIdx.x;
  int b  = blockIdx.y;
  int t0 = c * CHUNK;
  int lo = t0 - HALO; if (lo < 0) lo = 0;
  int hn = t0 - lo;                // halo count: 0 / 200 / 383
  int tid = threadIdx.x;
  int sub = tid & 7;               // lane within 8-lane group

  const float* srow = spec + (size_t)b * T_SZ * FRAME_F;
  float* grow = g0 + b * T_SZ;

  // ---- Phase A: g0 for own 200 frames; 2 frames per 8-lane group ----
  for (int gl = tid >> 3; gl < GRPS; gl += BLOCK / 8) {
    const float* base = srow + (size_t)(t0 + 2 * gl) * FRAME_F; // 644 floats
    float accA = 0.f, accB = 0.f;
    float pw0A = 0.f, pw160A = 0.f, pw0B = 0.f, pw160B = 0.f;
#pragma unroll
    for (int k = 0; k < 21; ++k) {
      int idx = k * 8 + sub;                           // f32x4 idx in [0,161)
      if (idx < 161) {
        f32x4 v = *(const f32x4*)(base + idx * 4);
        float s01 = v.x * v.x + v.y * v.y;
        float s23 = v.z * v.z + v.w * v.w;
        if (idx < 80) {
          accA += s01 + s23;
          if (idx == 0) pw0A = s01;                    // floats 0,1   (sub==0)
        } else if (idx == 80) {                        // straddle (sub==0)
          accA += s01; accB += s23;
          pw160A = s01;                                // floats 320,321
          pw0B   = s23;                                // floats 322,323
        } else {
          accB += s01 + s23;
          if (idx == 160) pw160B = s23;                // floats 642,643 (sub==0)
        }
      }
    }
#pragma unroll
    for (int off = 1; off < 8; off <<= 1) {
      accA += __shfl_xor(accA, off, 64);
      accB += __shfl_xor(accB, off, 64);
    }
    if (sub == 0) {                                    // endpoint pows live here
      float gA = sqrtf((2.f * accA - pw0A - pw160A) * (1.0f / 320.0f));
      float gB = sqrtf((2.f * accB - pw0B - pw160B) * (1.0f / 320.0f));
      xs[hn + 2 * gl]     = gA;
      xs[hn + 2 * gl + 1] = gB;
      f32x2 g; g.x = gA; g.y = gB;
      *(f32x2*)(grow + t0 + 2 * gl) = g;               // publish for successors
    }
  }
  __syncthreads();                 // own g0 in xs + issued to global

  // ---- Publish flag, then wait on the 2 predecessor chunks ----
  if (tid == 0) {
    __threadfence();                                   // release own g0
    atomicExch(&flags[b * NCHUNK + c], 1);
    for (int p = c - 1; p >= 0 && p >= c - 2; --p)
      while (atomicAdd(&flags[b * NCHUNK + p], 0) == 0) {}
    __threadfence();                                   // acquire their g0
  }
  __syncthreads();

  // ---- Load halo g0 [lo, t0) ----
  for (int i = tid; i < hn; i += BLOCK) xs[i] = grow[lo + i];
  __syncthreads();

  // ---- Phase B: truncated-window EMA for owned frames ----
  if (tid < CHUNK) {
    int t = t0 + tid;
    int s = t - HALO; if (s < 1) s = 1;
    float cc = (s == 1) ? xs[0] : 0.f;                 // lo==0 whenever s==1
    for (int k = s; k <= t; ++k) cc = cc * 0.9f + xs[k - lo] * 0.1f;
    gain_out[b * T_SZ + t] = cc;
    inv_s[tid] = 1.0f / (cc + 0.001f);
  }
  __syncthreads();

  // ---- Phase C: stream out = spec * inv (chunk cache-hot from phase A) ----
  size_t base4 = ((size_t)b * T_SZ + t0) * FRAME_F / 4;
  const f32x4* sp = (const f32x4*)spec + base4;
  f32x4*       op = (f32x4*)out  + base4;
#pragma unroll 4
  for (int i = tid; i < C4; i += BLOCK) {
    f32x4 v = sp[i];
    unsigned p0 = (unsigned)(2 * i);                   // local pair idx of (v.x,v.y)
    unsigned lf = p0 / 161u;                           // local frame (magic mul)
    unsigned r  = p0 - lf * 161u;
    unsigned lf1 = lf + (r == 160u);                   // frame of second pair
    float i0 = inv_s[lf];
    float i1 = inv_s[lf1];
    f32x4 rr;
    rr.x = v.x * i0; rr.y = v.y * i0;
    rr.z = v.z * i1; rr.w = v.w * i1;
    // nt store: keep the write stream from evicting spec
    __builtin_nontemporal_store(rr, op + i);
  }
}

extern "C" void kernel_launch(void* const* d_in, const int* in_sizes, int n_in,
                              void* d_out, int out_size, void* d_ws, size_t ws_size,
                              hipStream_t stream) {
  const float* spec = (const float*)d_in[0];
  float* out  = (float*)d_out;
  float* gain = out + N_SPEC;          // gain output lives in the d_out tail
  float* g0   = (float*)d_ws;          // 128000 f32
  int*   flags = (int*)(g0 + FRAMES);  // 640 ints

  hipMemsetAsync(flags, 0, B_SZ * NCHUNK * sizeof(int), stream);

  dim3 grid(NCHUNK, B_SZ);             // (20, 32) = 640 blocks
  k_flow<<<grid, BLOCK, 0, stream>>>(spec, out, gain, g0, flags);
}

// Round 14
// 93.913 us; speedup vs baseline: 1.3383x; 1.3383x over previous
//
#include <hip/hip_runtime.h>

// spec (32, 4000, 161, 2) f32.
//   pow[b,t,k]  = re^2 + im^2
//   g0[b,t]     = sqrt((2*sum(pow[1..159]) + pow[0] + pow[160]) / 320)
//   gain[b,t]   = EMA over t: c = 0.9c + 0.1*g0  (gain[b,0]=g0[b,0])
//   new_spec    = spec / (gain + 0.001)
// Outputs flat-concat: new_spec (41,216,000 f32) then gain (128,000 f32).
//
// Split structure (R11) with K3 ILP bump:
//  K1: g0, 2 frames per 8-lane group -> whole-line loads (proven ~25us).
//  K2: truncated-window EMA (0.9^384 < f32 eps -> exact), emits gain + inv.
//  K3: 4 f32x4 per thread (4 indep load/store pairs), nt stores.

typedef float f32x4 __attribute__((ext_vector_type(4)));
typedef float f32x2 __attribute__((ext_vector_type(2)));

#define B_SZ 32
#define T_SZ 4000
#define FRAME_F 322              // floats per frame (161 bins * 2)
#define FRAMES (B_SZ * T_SZ)     // 128000
#define N_SPEC ((size_t)FRAMES * FRAME_F)  // 41,216,000
#define N4 (N_SPEC / 4)          // 10,304,000 f32x4 (exact)
#define EMA_W 384                // 0.9^384 ~ 4e-18: below f32 resolution
#define HALO (EMA_W - 1)         // 383
#define BLOCK 256
#define NGROUPS (FRAMES / 2)     // 64000 8-lane groups (2 frames each)
#define U3 4                     // f32x4 per thread in K3
#define APB (BLOCK * U3)         // 1024 f32x4 per K3 block

// ---- K1: per-frame gain g0; 2 frames per 8-lane group, whole-line loads ----
__global__ __launch_bounds__(BLOCK) void k_frame_gain(
    const float* __restrict__ spec, float* __restrict__ g0) {
  int grp = (blockIdx.x * BLOCK + threadIdx.x) >> 3;   // group id
  int sub = threadIdx.x & 7;                           // lane in group
  if (grp >= NGROUPS) return;

  const float* base = spec + (size_t)grp * 644;        // 2 frames = 644 floats
  float accA = 0.f, accB = 0.f;
  float pw0A = 0.f, pw160A = 0.f, pw0B = 0.f, pw160B = 0.f;

#pragma unroll
  for (int k = 0; k < 21; ++k) {
    int idx = k * 8 + sub;                             // f32x4 idx in [0,161)
    if (idx < 161) {
      f32x4 v = *(const f32x4*)(base + idx * 4);
      float s01 = v.x * v.x + v.y * v.y;
      float s23 = v.z * v.z + v.w * v.w;
      if (idx < 80) {
        accA += s01 + s23;
        if (idx == 0) pw0A = s01;                      // floats 0,1   (sub==0)
      } else if (idx == 80) {                          // straddle (sub==0)
        accA += s01; accB += s23;
        pw160A = s01;                                  // floats 320,321
        pw0B   = s23;                                  // floats 322,323
      } else {
        accB += s01 + s23;
        if (idx == 160) pw160B = s23;                  // floats 642,643 (sub==0)
      }
    }
  }
#pragma unroll
  for (int off = 1; off < 8; off <<= 1) {
    accA += __shfl_xor(accA, off, 64);
    accB += __shfl_xor(accB, off, 64);
  }
  if (sub == 0) {                                      // endpoint pows live here
    f32x2 g;
    g.x = sqrtf((2.f * accA - pw0A - pw160A) * (1.0f / 320.0f));
    g.y = sqrtf((2.f * accB - pw0B - pw160B) * (1.0f / 320.0f));
    *(f32x2*)(g0 + 2 * grp) = g;
  }
}

// ---- K2: EMA via truncated window (exact for t < EMA_W); emits gain+inv ----
__global__ __launch_bounds__(BLOCK) void k_ema(
    const float* __restrict__ g0, float* __restrict__ gain_out,
    float* __restrict__ inv_out) {
  __shared__ float xs[HALO + 1 + 256];
  int b  = blockIdx.y;
  int t0 = blockIdx.x * 256;
  int lo = t0 - HALO; if (lo < 0) lo = 0;
  int hi = t0 + 256; if (hi > T_SZ) hi = T_SZ;     // exclusive
  int n  = hi - lo;
  const float* gb = g0 + b * T_SZ;

  for (int i = threadIdx.x; i < n; i += BLOCK) xs[i] = gb[lo + i];
  __syncthreads();

  int t = t0 + (int)threadIdx.x;
  if (t >= T_SZ) return;
  int s = t - HALO; if (s < 1) s = 1;
  float c = (s == 1) ? xs[0] : 0.f;                // lo==0 whenever s==1
  for (int k = s; k <= t; ++k) c = c * 0.9f + xs[k - lo] * 0.1f;
  gain_out[b * T_SZ + t] = c;
  inv_out[b * T_SZ + t]  = 1.0f / (c + 0.001f);
}

// ---- K3: out = spec * inv[frame]; 4 f32x4 per thread, nt stores ----
__global__ __launch_bounds__(BLOCK) void k_apply(
    const float* __restrict__ spec, const float* __restrict__ inv_g,
    float* __restrict__ out) {
  size_t b0 = (size_t)blockIdx.x * APB + threadIdx.x;
#pragma unroll
  for (int k = 0; k < U3; ++k) {
    size_t i = b0 + (size_t)k * BLOCK;               // f32x4 index
    if (i < N4) {
      f32x4 v = ((const f32x4*)spec)[i];
      unsigned p0 = (unsigned)(2 * i);               // pair idx of (v.x,v.y)
      unsigned f0 = p0 / 161u;                       // frame (magic mul)
      unsigned r  = p0 - f0 * 161u;
      unsigned f1 = f0 + (r == 160u);                // frame of second pair
      float i0 = inv_g[f0];
      float i1 = inv_g[f1];
      f32x4 rr;
      rr.x = v.x * i0; rr.y = v.y * i0;
      rr.z = v.z * i1; rr.w = v.w * i1;
      // nt store: don't evict spec from caches with the write stream
      __builtin_nontemporal_store(rr, (f32x4*)out + i);
    }
  }
}

extern "C" void kernel_launch(void* const* d_in, const int* in_sizes, int n_in,
                              void* d_out, int out_size, void* d_ws, size_t ws_size,
                              hipStream_t stream) {
  const float* spec = (const float*)d_in[0];
  float* out   = (float*)d_out;
  float* gain  = out + N_SPEC;       // gain output lives in the d_out tail
  float* g0    = (float*)d_ws;       // 128000 f32
  float* inv_g = g0 + FRAMES;        // 128000 f32

  // K1: 32 groups (64 frames) per block -> 2000 blocks
  k_frame_gain<<<NGROUPS * 8 / BLOCK, BLOCK, 0, stream>>>(spec, g0);

  // K2: (16, 32) grid
  dim3 g2((T_SZ + 255) / 256, B_SZ);
  k_ema<<<g2, BLOCK, 0, stream>>>(g0, gain, inv_g);

  // K3: 1024 f32x4 per block -> 10063 blocks
  k_apply<<<(int)((N4 + APB - 1) / APB), BLOCK, 0, stream>>>(spec, inv_g, out);
}